// Round 2
// baseline (149.339 us; speedup 1.0000x reference)
//
#include <hip/hip_runtime.h>
#include <hip/hip_bf16.h>
#include <math.h>

#define IMG 224
#define NLIB 1000
#define ZD 512
#define MAXK 8
#define NBLK 128
#define NTHR 512

// ---------------- ws layout (floats) ----------------
// [0, 1000)        dists
// [1008, 1024)     barrier uints (cnt0, gen0, cnt1, gen1) -- memset 0 each call
// [1024, +25088)   s0  (per-k channel-L2 sumsq, scale 0, 8*56*56)
// next 8*784       s1
// next 8*196       s2

__device__ __forceinline__ int clampk(int k) {
    if (k < 1) k = 1;
    if (k > MAXK) k = MAXK;
    return k;
}

__device__ __forceinline__ void gridbar(unsigned* cnt, unsigned* gen) {
    __threadfence();                       // release: flush my writes to coherent point
    __syncthreads();
    if (threadIdx.x == 0) {
        unsigned g = __hip_atomic_load(gen, __ATOMIC_RELAXED, __HIP_MEMORY_SCOPE_AGENT);
        unsigned old = __hip_atomic_fetch_add(cnt, 1u, __ATOMIC_ACQ_REL, __HIP_MEMORY_SCOPE_AGENT);
        if (old == NBLK - 1) {
            __hip_atomic_fetch_add(gen, 1u, __ATOMIC_RELEASE, __HIP_MEMORY_SCOPE_AGENT);
        } else {
            while (__hip_atomic_load(gen, __ATOMIC_ACQUIRE, __HIP_MEMORY_SCOPE_AGENT) == g)
                __builtin_amdgcn_s_sleep(2);
        }
    }
    __syncthreads();
    __threadfence();                       // acquire: invalidate stale cached lines
}

// min-over-k + sqrt + bilinear sample of one scale at output pixel (x,y)
__device__ __forceinline__ float scale_sample(const float* __restrict__ sk, int Win,
                                              float scl, int k, int x, int y) {
    int HW = Win * Win;
    float sxf = ((float)x + 0.5f) * scl - 0.5f;
    float syf = ((float)y + 0.5f) * scl - 0.5f;
    float fx = floorf(sxf), fy = floorf(syf);
    float wx = sxf - fx,    wy = syf - fy;
    int x0 = (int)fx, y0 = (int)fy;
    int x0c = min(max(x0, 0), Win - 1), x1c = min(max(x0 + 1, 0), Win - 1);
    int y0c = min(max(y0, 0), Win - 1), y1c = min(max(y0 + 1, 0), Win - 1);

    float v[4];
    int cx[4] = {x0c, x1c, x0c, x1c};
    int cy[4] = {y0c, y0c, y1c, y1c};
#pragma unroll
    for (int c = 0; c < 4; ++c) {
        int o = cy[c] * Win + cx[c];
        float mn = sk[o];
        for (int kk = 1; kk < k; ++kk) mn = fminf(mn, sk[kk * HW + o]);
        v[c] = sqrtf(mn);
    }
    return (1.f - wy) * ((1.f - wx) * v[0] + wx * v[1]) +
           wy * ((1.f - wx) * v[2] + wx * v[3]);
}

__global__ void __launch_bounds__(NTHR) k_fused(
        const float* __restrict__ z,
        const float* __restrict__ f0, const float* __restrict__ f1,
        const float* __restrict__ f2,
        const float* __restrict__ zlib,
        const float* __restrict__ l0, const float* __restrict__ l1,
        const float* __restrict__ l2,
        const int* __restrict__ kp,
        float* __restrict__ out,
        float* __restrict__ dists, unsigned* __restrict__ bar,
        float* __restrict__ s0, float* __restrict__ s1, float* __restrict__ s2) {

    __shared__ float pre[48 * 48];
    __shared__ float mid[48 * 32];
    __shared__ float wk[17];
    __shared__ int   idxs[MAXK];

    int tid = threadIdx.x;
    int lane = tid & 63, wave = tid >> 6;
    int k = clampk(*kp);

    // ---- Stage A: dists[e] = ||zlib[e] - z|| , one wave per entry ----
    int gw = blockIdx.x * (NTHR / 64) + wave;
    if (gw < NLIB) {
        const float4* row4 = (const float4*)(zlib + (size_t)gw * ZD);
        const float4* z4   = (const float4*)z;
        float4 a0 = row4[lane],      b0 = z4[lane];
        float4 a1 = row4[64 + lane], b1 = z4[64 + lane];
        float acc = 0.f, d;
        d = a0.x - b0.x; acc += d * d;  d = a0.y - b0.y; acc += d * d;
        d = a0.z - b0.z; acc += d * d;  d = a0.w - b0.w; acc += d * d;
        d = a1.x - b1.x; acc += d * d;  d = a1.y - b1.y; acc += d * d;
        d = a1.z - b1.z; acc += d * d;  d = a1.w - b1.w; acc += d * d;
#pragma unroll
        for (int off = 32; off > 0; off >>= 1) acc += __shfl_xor(acc, off, 64);
        if (lane == 0) dists[gw] = sqrtf(acc);
    }

    gridbar(bar + 0, bar + 1);

    // ---- Stage B: per-block redundant top-k (wave 0 only) ----
    if (wave == 0) {
        float vals[16];
#pragma unroll
        for (int j = 0; j < 16; ++j) {
            int e = lane + 64 * j;
            vals[j] = (e < NLIB) ? dists[e] : 3.4e38f;
        }
        float ssum = 0.f;
        for (int it = 0; it < k; ++it) {
            float bv = 3.4e38f; int bi = 0x7fffffff;
#pragma unroll
            for (int j = 0; j < 16; ++j) {
                int e = lane + 64 * j;
                if (vals[j] < bv) { bv = vals[j]; bi = e; }
            }
#pragma unroll
            for (int off = 1; off < 64; off <<= 1) {
                float ov = __shfl_xor(bv, off, 64);
                int   oi = __shfl_xor(bi, off, 64);
                if (ov < bv || (ov == bv && oi < bi)) { bv = ov; bi = oi; }
            }
#pragma unroll
            for (int j = 0; j < 16; ++j) {
                if (lane + 64 * j == bi) vals[j] = 3.4e38f;
            }
            if (lane == 0) { idxs[it] = bi; ssum += bv; }
        }
        if (lane == 0 && blockIdx.x == 0) out[0] = ssum / (float)k;
    }
    __syncthreads();

    // ---- Stage C: per-(pixel, kk) channel-L2 sumsq, all 3 scales ----
    {
        int gt = blockIdx.x * NTHR + tid;
        int S0 = k * 3136, S1 = k * 784, S2 = k * 196;
        if (gt < S0 + S1 + S2) {
            const float* fm; const float* lib; float* sout; int C, HW, p, kk;
            if (gt < S0)            { int q = gt;            kk = q / 3136; p = q % 3136; C = 64;  HW = 3136; fm = f0; lib = l0; sout = s0; }
            else if (gt < S0 + S1)  { int q = gt - S0;       kk = q / 784;  p = q % 784;  C = 128; HW = 784;  fm = f1; lib = l1; sout = s1; }
            else                    { int q = gt - S0 - S1;  kk = q / 196;  p = q % 196;  C = 256; HW = 196;  fm = f2; lib = l2; sout = s2; }
            const float* le = lib + (size_t)idxs[kk] * (size_t)C * HW + p;
            const float* fe = fm + p;
            float acc = 0.f;
#pragma unroll 8
            for (int c = 0; c < C; ++c) {
                float d = le[(size_t)c * HW] - fe[(size_t)c * HW];
                acc += d * d;
            }
            sout[kk * HW + p] = acc;
        }
    }

    gridbar(bar + 2, bar + 3);

    // ---- Stage D: 49 tiles of 32x32; upsample+min+sqrt into 48x48 halo tile,
    //      then separable 17-tap blur entirely in LDS ----
    int tile = blockIdx.x;
    if (tile >= 49) return;

    if (tid < 17) {
        float r = (float)(tid - 8) * 0.25f;     // t / sigma, sigma = 4
        wk[tid] = expf(-0.5f * r * r);
    }
    __syncthreads();
    float wsum = 0.f;
#pragma unroll
    for (int t = 0; t < 17; ++t) wsum += wk[t];
    float inv2 = 1.f / (wsum * wsum);

    int x0 = (tile % 7) * 32, y0 = (tile / 7) * 32;

    for (int i = tid; i < 48 * 48; i += NTHR) {
        int lx = i % 48, ly = i / 48;
        int gx = x0 - 8 + lx, gy = y0 - 8 + ly;
        float v = 0.f;
        if ((unsigned)gx < (unsigned)IMG && (unsigned)gy < (unsigned)IMG) {
            v = scale_sample(s0, 56, 0.25f,   k, gx, gy)
              + scale_sample(s1, 28, 0.125f,  k, gx, gy)
              + scale_sample(s2, 14, 0.0625f, k, gx, gy);
        }
        pre[i] = v;                             // zero padding outside image
    }
    __syncthreads();

    for (int i = tid; i < 48 * 32; i += NTHR) {
        int cx = i % 32, ly = i / 32;
        float acc = 0.f;
#pragma unroll
        for (int t = 0; t < 17; ++t) acc += wk[t] * pre[ly * 48 + cx + t];
        mid[ly * 32 + cx] = acc;
    }
    __syncthreads();

    for (int i = tid; i < 32 * 32; i += NTHR) {
        int ox = i % 32, oy = i / 32;
        float acc = 0.f;
#pragma unroll
        for (int t = 0; t < 17; ++t) acc += wk[t] * mid[(oy + t) * 32 + ox];
        out[1 + (y0 + oy) * IMG + (x0 + ox)] = acc * inv2;
    }
}

extern "C" void kernel_launch(void* const* d_in, const int* in_sizes, int n_in,
                              void* d_out, int out_size, void* d_ws, size_t ws_size,
                              hipStream_t stream) {
    const float* z    = (const float*)d_in[0];
    const float* f0   = (const float*)d_in[1];
    const float* f1   = (const float*)d_in[2];
    const float* f2   = (const float*)d_in[3];
    const float* zlib = (const float*)d_in[4];
    const float* l0   = (const float*)d_in[5];
    const float* l1   = (const float*)d_in[6];
    const float* l2   = (const float*)d_in[7];
    const int*   kp   = (const int*)d_in[8];
    float* out = (float*)d_out;

    float*    ws    = (float*)d_ws;
    float*    dists = ws;                       // 1000
    unsigned* bar   = (unsigned*)(ws + 1008);   // 4 uints
    float*    s0    = ws + 1024;                // 8*3136
    float*    s1    = s0 + MAXK * 3136;         // 8*784
    float*    s2    = s1 + MAXK * 784;          // 8*196

    hipMemsetAsync((char*)d_ws + 1008 * sizeof(float), 0, 64, stream);
    k_fused<<<NBLK, NTHR, 0, stream>>>(z, f0, f1, f2, zlib, l0, l1, l2, kp,
                                       out, dists, bar, s0, s1, s2);
}

// Round 3
// 49.406 us; speedup vs baseline: 3.0227x; 3.0227x over previous
//
#include <hip/hip_runtime.h>
#include <hip/hip_bf16.h>
#include <math.h>

#define IMG 224
#define NLIB 1000
#define ZD 512
#define MAXK 8
#define NTHR 512

// ws layout: [0,1000) dists

__device__ __forceinline__ int clampk(int k) {
    if (k < 1) k = 1;
    if (k > MAXK) k = MAXK;
    return k;
}

// ---- K1: dists[e] = ||zlib[e] - z||, one wave per entry ----
__global__ void __launch_bounds__(NTHR) k_dist(const float* __restrict__ z,
                                               const float* __restrict__ zlib,
                                               float* __restrict__ dists) {
    int lane = threadIdx.x & 63, wave = threadIdx.x >> 6;
    int gw = blockIdx.x * (NTHR / 64) + wave;
    if (gw >= NLIB) return;
    const float4* row4 = (const float4*)(zlib + (size_t)gw * ZD);
    const float4* z4   = (const float4*)z;
    float4 a0 = row4[lane],      b0 = z4[lane];
    float4 a1 = row4[64 + lane], b1 = z4[64 + lane];
    float acc = 0.f, d;
    d = a0.x - b0.x; acc += d * d;  d = a0.y - b0.y; acc += d * d;
    d = a0.z - b0.z; acc += d * d;  d = a0.w - b0.w; acc += d * d;
    d = a1.x - b1.x; acc += d * d;  d = a1.y - b1.y; acc += d * d;
    d = a1.z - b1.z; acc += d * d;  d = a1.w - b1.w; acc += d * d;
#pragma unroll
    for (int off = 32; off > 0; off >>= 1) acc += __shfl_xor(acc, off, 64);
    if (lane == 0) dists[gw] = sqrtf(acc);
}

// ---- K2: per-tile everything (topk + local channel-L2 + upsample + blur) ----
// grid: 14x14 tiles of 16x16 output pixels. 512 threads.
__global__ void __launch_bounds__(NTHR) k_main(
        const float* __restrict__ f0, const float* __restrict__ f1,
        const float* __restrict__ f2,
        const float* __restrict__ l0, const float* __restrict__ l1,
        const float* __restrict__ l2,
        const float* __restrict__ dists, const int* __restrict__ kp,
        float* __restrict__ out) {

    __shared__ float s0L[MAXK * 100];   // 10x10 window, scale 56
    __shared__ float s1L[MAXK * 36];    // 6x6 window, scale 28
    __shared__ float s2L[MAXK * 9];     // 3x3 window, scale 14
    __shared__ float pre[32 * 32];
    __shared__ float mid[32 * 16];
    __shared__ float wk[17];
    __shared__ int   idxs[MAXK];

    int tid = threadIdx.x;
    int lane = tid & 63, wave = tid >> 6;
    int k = clampk(*kp);

    int tx = blockIdx.x % 14, ty = blockIdx.x / 14;
    int x0 = tx * 16, y0 = ty * 16;

    // blur weights (wave 1 fills while wave 0 does topk)
    if (tid >= 64 && tid < 81) {
        float r = (float)(tid - 64 - 8) * 0.25f;    // t/sigma, sigma=4
        wk[tid - 64] = expf(-0.5f * r * r);
    }

    // ---- top-k (redundant per block; wave 0) ----
    if (wave == 0) {
        float vals[16];
#pragma unroll
        for (int j = 0; j < 16; ++j) {
            int e = lane + 64 * j;
            vals[j] = (e < NLIB) ? dists[e] : 3.4e38f;
        }
        float ssum = 0.f;
        for (int it = 0; it < k; ++it) {
            float bv = 3.4e38f; int bi = 0x7fffffff;
#pragma unroll
            for (int j = 0; j < 16; ++j) {
                if (vals[j] < bv) { bv = vals[j]; bi = lane + 64 * j; }
            }
#pragma unroll
            for (int off = 1; off < 64; off <<= 1) {
                float ov = __shfl_xor(bv, off, 64);
                int   oi = __shfl_xor(bi, off, 64);
                if (ov < bv || (ov == bv && oi < bi)) { bv = ov; bi = oi; }
            }
#pragma unroll
            for (int j = 0; j < 16; ++j) {
                if (lane + 64 * j == bi) vals[j] = 3.4e38f;
            }
            if (lane == 0) { idxs[it] = bi; ssum += bv; }
        }
        if (lane == 0 && blockIdx.x == 0) out[0] = ssum / (float)k;
    }
    __syncthreads();

    // ---- local per-k channel-L2 sumsq windows ----
    // window bases per scale (x0 mult of 16)
    int b0x = x0 / 4 - 3,  b0y = y0 / 4 - 3;    // 10x10 in 56x56
    int b1x = x0 / 8 - 2,  b1y = y0 / 8 - 2;    // 6x6  in 28x28
    int b2x = x0 / 16 - 1, b2y = y0 / 16 - 1;   // 3x3  in 14x14

    int NJ = k * 145;       // 100 + 36 + 9 jobs per k
    for (int j = tid; j < NJ; j += NTHR) {
        int kk = j / 145, r = j % 145;
        const float* fm; const float* lib; float* sL;
        int C, HW, Win, gx, gy, slot;
        if (r < 100) {
            int ly = r / 10, lx = r % 10;
            C = 64; HW = 3136; Win = 56; fm = f0; lib = l0;
            gx = min(max(b0x + lx, 0), Win - 1); gy = min(max(b0y + ly, 0), Win - 1);
            sL = s0L; slot = kk * 100 + r;
        } else if (r < 136) {
            int r2 = r - 100, ly = r2 / 6, lx = r2 % 6;
            C = 128; HW = 784; Win = 28; fm = f1; lib = l1;
            gx = min(max(b1x + lx, 0), Win - 1); gy = min(max(b1y + ly, 0), Win - 1);
            sL = s1L; slot = kk * 36 + r2;
        } else {
            int r3 = r - 136, ly = r3 / 3, lx = r3 % 3;
            C = 256; HW = 196; Win = 14; fm = f2; lib = l2;
            gx = min(max(b2x + lx, 0), Win - 1); gy = min(max(b2y + ly, 0), Win - 1);
            sL = s2L; slot = kk * 9 + r3;
        }
        int p = gy * Win + gx;
        const float* le = lib + (size_t)idxs[kk] * (size_t)C * HW + p;
        const float* fe = fm + p;
        float acc = 0.f;
#pragma unroll 8
        for (int c = 0; c < C; ++c) {
            float d = le[(size_t)c * HW] - fe[(size_t)c * HW];
            acc += d * d;
        }
        sL[slot] = acc;
    }
    __syncthreads();

    float wsum = 0.f;
#pragma unroll
    for (int t = 0; t < 17; ++t) wsum += wk[t];
    float inv2 = 1.f / (wsum * wsum);

    // ---- upsample + min-over-k + sqrt into 32x32 halo tile ----
    for (int i = tid; i < 32 * 32; i += NTHR) {
        int lx = i % 32, ly = i / 32;
        int gx = x0 - 8 + lx, gy = y0 - 8 + ly;
        float v = 0.f;
        if ((unsigned)gx < (unsigned)IMG && (unsigned)gy < (unsigned)IMG) {
            // three scales
            const float* sLs[3] = { s0L, s1L, s2L };
            const int   Wl[3]  = { 10, 6, 3 };
            const int   Ws[3]  = { 56, 28, 14 };
            const int   str[3] = { 100, 36, 9 };
            const int   bx[3]  = { b0x, b1x, b2x };
            const int   by[3]  = { b0y, b1y, b2y };
            const float scl[3] = { 0.25f, 0.125f, 0.0625f };
#pragma unroll
            for (int s = 0; s < 3; ++s) {
                int Win = Ws[s];
                float sxf = ((float)gx + 0.5f) * scl[s] - 0.5f;
                float syf = ((float)gy + 0.5f) * scl[s] - 0.5f;
                float fx = floorf(sxf), fy = floorf(syf);
                float wx = sxf - fx,    wy = syf - fy;
                int ix = (int)fx, iy = (int)fy;
                int x0c = min(max(ix, 0), Win - 1) - bx[s];
                int x1c = min(max(ix + 1, 0), Win - 1) - bx[s];
                int y0c = min(max(iy, 0), Win - 1) - by[s];
                int y1c = min(max(iy + 1, 0), Win - 1) - by[s];
                const float* sL = sLs[s];
                int o00 = y0c * Wl[s] + x0c, o10 = y0c * Wl[s] + x1c;
                int o01 = y1c * Wl[s] + x0c, o11 = y1c * Wl[s] + x1c;
                float m00 = sL[o00], m10 = sL[o10], m01 = sL[o01], m11 = sL[o11];
                for (int kk = 1; kk < k; ++kk) {
                    const float* b = sL + kk * str[s];
                    m00 = fminf(m00, b[o00]); m10 = fminf(m10, b[o10]);
                    m01 = fminf(m01, b[o01]); m11 = fminf(m11, b[o11]);
                }
                float v00 = sqrtf(m00), v10 = sqrtf(m10);
                float v01 = sqrtf(m01), v11 = sqrtf(m11);
                v += (1.f - wy) * ((1.f - wx) * v00 + wx * v10)
                   + wy * ((1.f - wx) * v01 + wx * v11);
            }
        }
        pre[i] = v;     // zero padding outside the image
    }
    __syncthreads();

    // ---- horizontal blur: 32 rows x 16 cols ----
    for (int i = tid; i < 32 * 16; i += NTHR) {
        int cx = i % 16, ly = i / 16;
        float acc = 0.f;
#pragma unroll
        for (int t = 0; t < 17; ++t) acc += wk[t] * pre[ly * 32 + cx + t];
        mid[ly * 16 + cx] = acc;
    }
    __syncthreads();

    // ---- vertical blur + store ----
    for (int i = tid; i < 16 * 16; i += NTHR) {
        int ox = i % 16, oy = i / 16;
        float acc = 0.f;
#pragma unroll
        for (int t = 0; t < 17; ++t) acc += wk[t] * mid[(oy + t) * 16 + ox];
        out[1 + (y0 + oy) * IMG + (x0 + ox)] = acc * inv2;
    }
}

extern "C" void kernel_launch(void* const* d_in, const int* in_sizes, int n_in,
                              void* d_out, int out_size, void* d_ws, size_t ws_size,
                              hipStream_t stream) {
    const float* z    = (const float*)d_in[0];
    const float* f0   = (const float*)d_in[1];
    const float* f1   = (const float*)d_in[2];
    const float* f2   = (const float*)d_in[3];
    const float* zlib = (const float*)d_in[4];
    const float* l0   = (const float*)d_in[5];
    const float* l1   = (const float*)d_in[6];
    const float* l2   = (const float*)d_in[7];
    const int*   kp   = (const int*)d_in[8];
    float* out = (float*)d_out;
    float* dists = (float*)d_ws;

    k_dist<<<(NLIB * 64 + NTHR - 1) / NTHR, NTHR, 0, stream>>>(z, zlib, dists);
    k_main<<<196, NTHR, 0, stream>>>(f0, f1, f2, l0, l1, l2, dists, kp, out);
}

// Round 4
// 24.257 us; speedup vs baseline: 6.1565x; 2.0368x over previous
//
#include <hip/hip_runtime.h>
#include <hip/hip_bf16.h>
#include <math.h>

#define IMG 224
#define NLIB 1000
#define ZD 512
#define MAXK 8
#define NTHR 512
#define STHR 256

// ---------------- ws layout (floats) ----------------
// [0, 1000)                 dists
// [1024, +MAXK*3136)        s0   sumsq, scale 56   (C=64, 1 part)
// next 2*MAXK*784           s1   partial sumsq, scale 28 (C=128 -> 2 parts of 64)
// next 4*MAXK*196           s2   partial sumsq, scale 14 (C=256 -> 4 parts of 64)

__device__ __forceinline__ int clampk(int k) {
    if (k < 1) k = 1;
    if (k > MAXK) k = MAXK;
    return k;
}

// ---- K1: dists[e] = ||zlib[e] - z||, one wave per entry ----
__global__ void __launch_bounds__(NTHR) k_dist(const float* __restrict__ z,
                                               const float* __restrict__ zlib,
                                               float* __restrict__ dists) {
    int lane = threadIdx.x & 63, wave = threadIdx.x >> 6;
    int gw = blockIdx.x * (NTHR / 64) + wave;
    if (gw >= NLIB) return;
    const float4* row4 = (const float4*)(zlib + (size_t)gw * ZD);
    const float4* z4   = (const float4*)z;
    float4 a0 = row4[lane],      b0 = z4[lane];
    float4 a1 = row4[64 + lane], b1 = z4[64 + lane];
    float acc = 0.f, d;
    d = a0.x - b0.x; acc += d * d;  d = a0.y - b0.y; acc += d * d;
    d = a0.z - b0.z; acc += d * d;  d = a0.w - b0.w; acc += d * d;
    d = a1.x - b1.x; acc += d * d;  d = a1.y - b1.y; acc += d * d;
    d = a1.z - b1.z; acc += d * d;  d = a1.w - b1.w; acc += d * d;
#pragma unroll
    for (int off = 32; off > 0; off >>= 1) acc += __shfl_xor(acc, off, 64);
    if (lane == 0) dists[gw] = sqrtf(acc);
}

// ---- K2: inline topk + exact channel-L2 partial sums, 64-load chains ----
__global__ void __launch_bounds__(STHR) k_score(
        const float* __restrict__ f0, const float* __restrict__ f1,
        const float* __restrict__ f2,
        const float* __restrict__ l0, const float* __restrict__ l1,
        const float* __restrict__ l2,
        const float* __restrict__ dists, const int* __restrict__ kp,
        float* __restrict__ out,
        float* __restrict__ s0, float* __restrict__ s1, float* __restrict__ s2) {

    __shared__ int idxs[MAXK];
    int tid = threadIdx.x;
    int lane = tid & 63, wave = tid >> 6;
    int k = clampk(*kp);

    // wave-parallel top-k (redundant per block; deterministic tie-break)
    if (wave == 0) {
        float vals[16];
#pragma unroll
        for (int j = 0; j < 16; ++j) {
            int e = lane + 64 * j;
            vals[j] = (e < NLIB) ? dists[e] : 3.4e38f;
        }
        float ssum = 0.f;
        for (int it = 0; it < k; ++it) {
            float bv = 3.4e38f; int bi = 0x7fffffff;
#pragma unroll
            for (int j = 0; j < 16; ++j) {
                if (vals[j] < bv) { bv = vals[j]; bi = lane + 64 * j; }
            }
#pragma unroll
            for (int off = 1; off < 64; off <<= 1) {
                float ov = __shfl_xor(bv, off, 64);
                int   oi = __shfl_xor(bi, off, 64);
                if (ov < bv || (ov == bv && oi < bi)) { bv = ov; bi = oi; }
            }
#pragma unroll
            for (int j = 0; j < 16; ++j) {
                if (lane + 64 * j == bi) vals[j] = 3.4e38f;
            }
            if (lane == 0) { idxs[it] = bi; ssum += bv; }
        }
        if (lane == 0 && blockIdx.x == 0) out[0] = ssum / (float)k;
    }
    __syncthreads();

    // jobs: [k*3136 scale0] [k*1568 scale1 (2 parts)] [k*784 scale2 (4 parts)]
    int j = blockIdx.x * STHR + tid;
    int n0 = k * 3136, n1 = k * 1568, n2 = k * 784;
    if (j >= n0 + n1 + n2) return;

    const float* fmp; const float* lbp; float* op;
    int kk, p, cbase, HW, Cfull;
    if (j < n0) {
        kk = j / 3136; p = j % 3136; cbase = 0;
        HW = 3136; Cfull = 64; fmp = f0; lbp = l0;
        op = s0 + kk * 3136 + p;
    } else if (j < n0 + n1) {
        int r = j - n0; kk = r / 1568; int q = r % 1568;
        int part = q / 784; p = q % 784; cbase = part * 64;
        HW = 784; Cfull = 128; fmp = f1; lbp = l1;
        op = s1 + part * (MAXK * 784) + kk * 784 + p;
    } else {
        int r = j - n0 - n1; kk = r / 784; int q = r % 784;
        int part = q / 196; p = q % 196; cbase = part * 64;
        HW = 196; Cfull = 256; fmp = f2; lbp = l2;
        op = s2 + part * (MAXK * 196) + kk * 196 + p;
    }

    const float* le = lbp + (size_t)idxs[kk] * (size_t)Cfull * HW + (size_t)cbase * HW + p;
    const float* fe = fmp + (size_t)cbase * HW + p;
    float acc = 0.f;
#pragma unroll 8
    for (int c = 0; c < 64; ++c) {
        float d = le[(size_t)c * HW] - fe[(size_t)c * HW];
        acc += d * d;
    }
    *op = acc;
}

// bilinear sample from an LDS window (already min-over-k + sqrt)
__device__ __forceinline__ float bilin(const float* __restrict__ msm, int Wl, int Win,
                                       int bx, int by, float scl, int gx, int gy) {
    float sxf = ((float)gx + 0.5f) * scl - 0.5f;
    float syf = ((float)gy + 0.5f) * scl - 0.5f;
    float fx = floorf(sxf), fy = floorf(syf);
    float wx = sxf - fx,    wy = syf - fy;
    int ix = (int)fx, iy = (int)fy;
    int x0c = min(max(ix, 0), Win - 1) - bx, x1c = min(max(ix + 1, 0), Win - 1) - bx;
    int y0c = min(max(iy, 0), Win - 1) - by, y1c = min(max(iy + 1, 0), Win - 1) - by;
    float v00 = msm[y0c * Wl + x0c], v10 = msm[y0c * Wl + x1c];
    float v01 = msm[y1c * Wl + x0c], v11 = msm[y1c * Wl + x1c];
    return (1.f - wy) * ((1.f - wx) * v00 + wx * v10) +
           wy * ((1.f - wx) * v01 + wx * v11);
}

// ---- K3: per-tile min+sqrt window staging, upsample, blur (all LDS) ----
__global__ void __launch_bounds__(NTHR) k_tile(
        const float* __restrict__ s0, const float* __restrict__ s1,
        const float* __restrict__ s2, const int* __restrict__ kp,
        float* __restrict__ out) {

    __shared__ float msm0[100];     // 10x10 window, scale 56
    __shared__ float msm1[36];      // 6x6 window, scale 28
    __shared__ float msm2[9];       // 3x3 window, scale 14
    __shared__ float pre[32 * 32];
    __shared__ float mid[32 * 16];
    __shared__ float wk[17];

    int tid = threadIdx.x;
    int k = clampk(*kp);
    int tx = blockIdx.x % 14, ty = blockIdx.x / 14;
    int x0 = tx * 16, y0 = ty * 16;
    int b0x = x0 / 4 - 3,  b0y = y0 / 4 - 3;
    int b1x = x0 / 8 - 2,  b1y = y0 / 8 - 2;
    int b2x = x0 / 16 - 1, b2y = y0 / 16 - 1;

    if (tid < 17) {
        float r = (float)(tid - 8) * 0.25f;     // t/sigma, sigma=4
        wk[tid] = expf(-0.5f * r * r);
    }

    // stage windows: min over k of (sum of parts), then sqrt — once per src pixel
    if (tid >= 32 && tid < 32 + 145) {          // different waves than wk-fill
        int i = tid - 32;
        float m = 3.4e38f;
        if (i < 100) {
            int ly = i / 10, lx = i % 10;
            int gx = min(max(b0x + lx, 0), 55), gy = min(max(b0y + ly, 0), 55);
            int p = gy * 56 + gx;
            for (int kk = 0; kk < k; ++kk) m = fminf(m, s0[kk * 3136 + p]);
            msm0[i] = sqrtf(m);
        } else if (i < 136) {
            int r = i - 100; int ly = r / 6, lx = r % 6;
            int gx = min(max(b1x + lx, 0), 27), gy = min(max(b1y + ly, 0), 27);
            int p = gy * 28 + gx;
            for (int kk = 0; kk < k; ++kk) {
                float v = s1[kk * 784 + p] + s1[MAXK * 784 + kk * 784 + p];
                m = fminf(m, v);
            }
            msm1[r] = sqrtf(m);
        } else {
            int r = i - 136; int ly = r / 3, lx = r % 3;
            int gx = min(max(b2x + lx, 0), 13), gy = min(max(b2y + ly, 0), 13);
            int p = gy * 14 + gx;
            for (int kk = 0; kk < k; ++kk) {
                float v = s2[kk * 196 + p] + s2[MAXK * 196 + kk * 196 + p]
                        + s2[2 * MAXK * 196 + kk * 196 + p] + s2[3 * MAXK * 196 + kk * 196 + p];
                m = fminf(m, v);
            }
            msm2[r] = sqrtf(m);
        }
    }
    __syncthreads();

    float wsum = 0.f;
#pragma unroll
    for (int t = 0; t < 17; ++t) wsum += wk[t];
    float inv2 = 1.f / (wsum * wsum);

    // upsample + sum of 3 scales into 32x32 halo tile (zero outside image)
    for (int i = tid; i < 32 * 32; i += NTHR) {
        int lx = i % 32, ly = i / 32;
        int gx = x0 - 8 + lx, gy = y0 - 8 + ly;
        float v = 0.f;
        if ((unsigned)gx < (unsigned)IMG && (unsigned)gy < (unsigned)IMG) {
            v = bilin(msm0, 10, 56, b0x, b0y, 0.25f,   gx, gy)
              + bilin(msm1, 6,  28, b1x, b1y, 0.125f,  gx, gy)
              + bilin(msm2, 3,  14, b2x, b2y, 0.0625f, gx, gy);
        }
        pre[i] = v;
    }
    __syncthreads();

    // horizontal blur: 32 rows x 16 center cols
    {
        int i = tid;
        if (i < 32 * 16) {
            int cx = i % 16, ly = i / 16;
            float acc = 0.f;
#pragma unroll
            for (int t = 0; t < 17; ++t) acc += wk[t] * pre[ly * 32 + cx + t];
            mid[ly * 16 + cx] = acc;
        }
    }
    __syncthreads();

    // vertical blur + store
    if (tid < 16 * 16) {
        int ox = tid % 16, oy = tid / 16;
        float acc = 0.f;
#pragma unroll
        for (int t = 0; t < 17; ++t) acc += wk[t] * mid[(oy + t) * 16 + ox];
        out[1 + (y0 + oy) * IMG + (x0 + ox)] = acc * inv2;
    }
}

extern "C" void kernel_launch(void* const* d_in, const int* in_sizes, int n_in,
                              void* d_out, int out_size, void* d_ws, size_t ws_size,
                              hipStream_t stream) {
    const float* z    = (const float*)d_in[0];
    const float* f0   = (const float*)d_in[1];
    const float* f1   = (const float*)d_in[2];
    const float* f2   = (const float*)d_in[3];
    const float* zlib = (const float*)d_in[4];
    const float* l0   = (const float*)d_in[5];
    const float* l1   = (const float*)d_in[6];
    const float* l2   = (const float*)d_in[7];
    const int*   kp   = (const int*)d_in[8];
    float* out = (float*)d_out;

    float* ws    = (float*)d_ws;
    float* dists = ws;                          // 1000
    float* s0    = ws + 1024;                   // MAXK*3136
    float* s1    = s0 + MAXK * 3136;            // 2*MAXK*784
    float* s2    = s1 + 2 * MAXK * 784;         // 4*MAXK*196

    k_dist<<<(NLIB + 7) / 8, NTHR, 0, stream>>>(z, zlib, dists);

    int njobs = MAXK * (3136 + 1568 + 784);     // 43904 (grid for max k)
    k_score<<<(njobs + STHR - 1) / STHR, STHR, 0, stream>>>(
        f0, f1, f2, l0, l1, l2, dists, kp, out, s0, s1, s2);

    k_tile<<<196, NTHR, 0, stream>>>(s0, s1, s2, kp, out);
}